// Round 1
// 1327.297 us; speedup vs baseline: 2.7121x; 2.7121x over previous
//
#include <hip/hip_runtime.h>

#define N_ROWS 400000
#define M_SEG  100000
#define EMB    128
#define SSTR   132      // seg_sum padded row stride (floats)
#define AST    168      // LDS A-stride (f16 elems) for K=160 (129 zero-padded)
#define S1     5        // K-steps for K=129 layers (padded to 160)
#define S2     8        // K-steps for K=256 layers

typedef _Float16 f16x8 __attribute__((ext_vector_type(8)));
typedef float    f32x4 __attribute__((ext_vector_type(4)));

__device__ __forceinline__ unsigned short h_bits(_Float16 h) {
    unsigned short u; __builtin_memcpy(&u, &h, 2); return u;
}
__device__ __forceinline__ float softplus_f(float x) {
    return fmaxf(x, 0.f) + __logf(1.f + __expf(-fabsf(x)));
}

// ---------------------------------------------------------------------------
// K-loop: 4 M-tiles x 4 N-tiles per wave, f16 hi/lo 3-product MFMA.
// A-frag: row = lane&15 (cc), k = s*32 + (lane>>4)*8 + j   (16B ds_read)
// B-frag: prepacked so each lane's 8 elems are one coalesced dwordx4.
// C/D   : col = lane&15 (cc), row = 4*(lane>>4) + reg      (m89-verified)
// ---------------------------------------------------------------------------
#define KLOOP(STEPS, AIDX, BH, BL)                                                  \
  for (int s = 0; s < (STEPS); ++s) {                                               \
    f16x8 ah[4], al[4], bhv[4], blv[4];                                             \
    _Pragma("unroll")                                                               \
    for (int mt = 0; mt < 4; ++mt) {                                                \
      const int ai = (AIDX);                                                        \
      ah[mt] = *reinterpret_cast<const f16x8*>(&lds[0][ai]);                        \
      al[mt] = *reinterpret_cast<const f16x8*>(&lds[1][ai]);                        \
    }                                                                               \
    _Pragma("unroll")                                                               \
    for (int nt = 0; nt < 4; ++nt) {                                                \
      const size_t bo = (((size_t)s * 16 + w * 4 + nt) * 64 + lane) * 8;            \
      bhv[nt] = *reinterpret_cast<const f16x8*>(&(BH)[bo]);                         \
      blv[nt] = *reinterpret_cast<const f16x8*>(&(BL)[bo]);                         \
    }                                                                               \
    _Pragma("unroll")                                                               \
    for (int mt = 0; mt < 4; ++mt) {                                                \
      _Pragma("unroll")                                                             \
      for (int nt = 0; nt < 4; ++nt) {                                              \
        acc[mt][nt] = __builtin_amdgcn_mfma_f32_16x16x32_f16(ah[mt], bhv[nt], acc[mt][nt], 0, 0, 0); \
        acc[mt][nt] = __builtin_amdgcn_mfma_f32_16x16x32_f16(al[mt], bhv[nt], acc[mt][nt], 0, 0, 0); \
        acc[mt][nt] = __builtin_amdgcn_mfma_f32_16x16x32_f16(ah[mt], blv[nt], acc[mt][nt], 0, 0, 0); \
      }                                                                             \
    }                                                                               \
  }

// softplus(acc) -> hi/lo f16 planes in LDS, stride 256, XOR-swizzled (G4 fix:
// stride-256 rows are a 32-way bank conflict; byte ^= (row&7)<<4).
#define WRITE_ACT_LDS()                                                   \
  _Pragma("unroll")                                                       \
  for (int mt = 0; mt < 4; ++mt)                                          \
    _Pragma("unroll")                                                     \
    for (int nt = 0; nt < 4; ++nt)                                        \
      _Pragma("unroll")                                                   \
      for (int r = 0; r < 4; ++r) {                                       \
        const float hv = softplus_f(acc[mt][nt][r]);                      \
        const int row = mt * 16 + 4 * g + r;                              \
        const int col = w * 64 + nt * 16 + cc;                            \
        const int si  = ((row * 256 + col) ^ ((row & 7) << 3));           \
        const _Float16 hh = (_Float16)hv;                                 \
        lds[0][si] = h_bits(hh);                                          \
        lds[1][si] = h_bits((_Float16)(hv - (float)hh));                  \
      }

#define ACC_INIT_BIAS(BPTR)                                   \
  _Pragma("unroll")                                           \
  for (int nt = 0; nt < 4; ++nt) {                            \
    const float b = (BPTR)[w * 64 + nt * 16 + cc];            \
    _Pragma("unroll")                                         \
    for (int mt = 0; mt < 4; ++mt)                            \
      _Pragma("unroll")                                       \
      for (int r = 0; r < 4; ++r) acc[mt][nt][r] = b;         \
  }

#define AIDX_L1 ((mt * 16 + cc) * AST + s * 32 + g * 8)
#define AIDX_SW ((((mt * 16 + cc) * 256 + s * 32 + g * 8)) ^ ((cc & 7) << 3))

// ---------------------------------------------------------------------------
// Kernel 1: segment sum of [comp_emb | mole_frac] plus counts, via atomics.
// ---------------------------------------------------------------------------
__global__ __launch_bounds__(256) void segsum_kernel(
    const float* __restrict__ comp_emb, const float* __restrict__ mf,
    const int* __restrict__ seg, float* __restrict__ seg_sum,
    float* __restrict__ counts) {
    int i = blockIdx.x * 256 + threadIdx.x;
    if (i >= N_ROWS * 130) return;
    int row = i / 130;
    int col = i - row * 130;
    int s = seg[row];
    if (col < EMB) {
        atomicAdd(&seg_sum[(size_t)s * SSTR + col], comp_emb[(size_t)row * EMB + col]);
    } else if (col == EMB) {
        atomicAdd(&seg_sum[(size_t)s * SSTR + EMB], mf[row]);
    } else {
        atomicAdd(&counts[s], 1.f);
    }
}

// ---------------------------------------------------------------------------
// Kernel 2: prepack weight matrix W[K][256] into MFMA-fragment-ordered f16
// hi/lo planes: ph[((s*16+nt)*64+lane)*8 + j] = hi(W[s*32+(lane>>4)*8+j][nt*16+(lane&15)])
// ---------------------------------------------------------------------------
__global__ __launch_bounds__(256) void pack_w_kernel(
    const float* __restrict__ W, int K, int steps,
    unsigned short* __restrict__ ph, unsigned short* __restrict__ pl) {
    int idx = blockIdx.x * 256 + threadIdx.x;
    if (idx >= steps * 1024) return;
    int lane = idx & 63, t = idx >> 6, nt = t & 15, s = t >> 4;
    int c  = nt * 16 + (lane & 15);
    int k0 = s * 32 + (lane >> 4) * 8;
    unsigned short h[8], l[8];
    #pragma unroll
    for (int j = 0; j < 8; ++j) {
        int k = k0 + j;
        float v = (k < K) ? W[(size_t)k * 256 + c] : 0.f;
        _Float16 hh = (_Float16)v;
        h[j] = h_bits(hh);
        l[j] = h_bits((_Float16)(v - (float)hh));
    }
    __builtin_memcpy(&ph[(size_t)idx * 8], h, 16);
    __builtin_memcpy(&pl[(size_t)idx * 8], l, 16);
}

// ---------------------------------------------------------------------------
// Kernel 3: mixture pipeline, MFMA. 64 pooled rows/block, 256 thr (4 waves).
//   h   = softplus(pooled @ iW1 + ib1)        K=129
//   ctx = softplus(h @ iW2 + ib2)             K=256
//   z   = ctx @ gW1[129:,:] + gb1             K=256   (linear, stored f32)
// ---------------------------------------------------------------------------
__global__ __launch_bounds__(256, 2) void mix_mfma_kernel(
    const float* __restrict__ seg_sum, const float* __restrict__ counts,
    const unsigned short* __restrict__ i1h, const unsigned short* __restrict__ i1l,
    const float* __restrict__ ib1,
    const unsigned short* __restrict__ i2h, const unsigned short* __restrict__ i2l,
    const float* __restrict__ ib2,
    const unsigned short* __restrict__ gzh, const unsigned short* __restrict__ gzl,
    const float* __restrict__ gb1,
    float* __restrict__ z) {
    __shared__ unsigned short lds[2][64 * 256];   // 64 KB exactly
    const int m0  = blockIdx.x * 64;
    const int tid = threadIdx.x;
    const int w = tid >> 6, lane = tid & 63, g = lane >> 4, cc = lane & 15;

    // stage pooled rows (seg_sum/counts) as f16 hi/lo, stride AST
    for (int i = tid; i < 64 * 42; i += 256) {
        int r = i / 42, c4 = i - r * 42;
        int m = m0 + r;
        float x0 = 0.f, x1 = 0.f, x2 = 0.f, x3 = 0.f;
        if (m < M_SEG && c4 <= 32) {
            float inv = 1.f / fmaxf(counts[m], 1.f);
            if (c4 < 32) {
                const float4 v = *reinterpret_cast<const float4*>(&seg_sum[(size_t)m * SSTR + c4 * 4]);
                x0 = v.x * inv; x1 = v.y * inv; x2 = v.z * inv; x3 = v.w * inv;
            } else {
                x0 = seg_sum[(size_t)m * SSTR + EMB] * inv;
            }
        }
        _Float16 h0 = (_Float16)x0, h1 = (_Float16)x1, h2 = (_Float16)x2, h3 = (_Float16)x3;
        uint2 hv = make_uint2((unsigned)h_bits(h0) | ((unsigned)h_bits(h1) << 16),
                              (unsigned)h_bits(h2) | ((unsigned)h_bits(h3) << 16));
        uint2 lv = make_uint2((unsigned)h_bits((_Float16)(x0 - (float)h0)) |
                              ((unsigned)h_bits((_Float16)(x1 - (float)h1)) << 16),
                              (unsigned)h_bits((_Float16)(x2 - (float)h2)) |
                              ((unsigned)h_bits((_Float16)(x3 - (float)h3)) << 16));
        *reinterpret_cast<uint2*>(&lds[0][r * AST + c4 * 4]) = hv;
        *reinterpret_cast<uint2*>(&lds[1][r * AST + c4 * 4]) = lv;
    }
    __syncthreads();

    f32x4 acc[4][4];
    // layer 1
    ACC_INIT_BIAS(ib1)
    KLOOP(S1, AIDX_L1, i1h, i1l)
    __syncthreads();
    WRITE_ACT_LDS()
    __syncthreads();
    // layer 2
    ACC_INIT_BIAS(ib2)
    KLOOP(S2, AIDX_SW, i2h, i2l)
    __syncthreads();
    WRITE_ACT_LDS()          // ctx overwrites h (barrier above protects readers)
    __syncthreads();
    // layer 3: z = ctx @ gW1c + gb1 (linear)
    ACC_INIT_BIAS(gb1)
    KLOOP(S2, AIDX_SW, gzh, gzl)
    #pragma unroll
    for (int mt = 0; mt < 4; ++mt)
        #pragma unroll
        for (int nt = 0; nt < 4; ++nt)
            #pragma unroll
            for (int r = 0; r < 4; ++r) {
                int m = m0 + mt * 16 + 4 * g + r;
                if (m < M_SEG)
                    z[(size_t)m * 256 + w * 64 + nt * 16 + cc] = acc[mt][nt][r];
            }
}

// ---------------------------------------------------------------------------
// Kernel 4: gate MLP, MFMA. 64 rows/block, 256 thr (4 waves x 64 cols).
//   acc = z[seg[row]]  (ctx-part of layer1 + gb1, pre-folded)
//   g   = softplus(acc + [emb|mf] @ gW1[:129])     K=129
//   out = softplus(g @ gW2 + gb2)                  K=256
// ---------------------------------------------------------------------------
__global__ __launch_bounds__(256, 2) void gate_mfma_kernel(
    const float* __restrict__ comp_emb, const float* __restrict__ mf,
    const int* __restrict__ seg, const float* __restrict__ z,
    const unsigned short* __restrict__ g1h, const unsigned short* __restrict__ g1l,
    const unsigned short* __restrict__ g2h, const unsigned short* __restrict__ g2l,
    const float* __restrict__ gb2, float* __restrict__ out) {
    __shared__ unsigned short lds[2][64 * 256];   // 64 KB exactly
    const int n0  = blockIdx.x * 64;
    const int tid = threadIdx.x;
    const int w = tid >> 6, lane = tid & 63, g = lane >> 4, cc = lane & 15;

    // accumulator init: gather z[seg[row]] (issued early, overlaps staging)
    f32x4 acc[4][4];
    int rs[4][4];
    #pragma unroll
    for (int mt = 0; mt < 4; ++mt)
        #pragma unroll
        for (int r = 0; r < 4; ++r)
            rs[mt][r] = seg[n0 + mt * 16 + 4 * g + r];
    #pragma unroll
    for (int mt = 0; mt < 4; ++mt)
        #pragma unroll
        for (int nt = 0; nt < 4; ++nt)
            #pragma unroll
            for (int r = 0; r < 4; ++r)
                acc[mt][nt][r] = z[(size_t)rs[mt][r] * 256 + w * 64 + nt * 16 + cc];

    // stage [emb | mf | 0pad] as f16 hi/lo, stride AST
    for (int i = tid; i < 64 * 42; i += 256) {
        int r = i / 42, c4 = i - r * 42;
        int row = n0 + r;
        float x0 = 0.f, x1 = 0.f, x2 = 0.f, x3 = 0.f;
        if (c4 < 32) {
            const float4 v = *reinterpret_cast<const float4*>(&comp_emb[(size_t)row * EMB + c4 * 4]);
            x0 = v.x; x1 = v.y; x2 = v.z; x3 = v.w;
        } else if (c4 == 32) {
            x0 = mf[row];
        }
        _Float16 h0 = (_Float16)x0, h1 = (_Float16)x1, h2 = (_Float16)x2, h3 = (_Float16)x3;
        uint2 hv = make_uint2((unsigned)h_bits(h0) | ((unsigned)h_bits(h1) << 16),
                              (unsigned)h_bits(h2) | ((unsigned)h_bits(h3) << 16));
        uint2 lv = make_uint2((unsigned)h_bits((_Float16)(x0 - (float)h0)) |
                              ((unsigned)h_bits((_Float16)(x1 - (float)h1)) << 16),
                              (unsigned)h_bits((_Float16)(x2 - (float)h2)) |
                              ((unsigned)h_bits((_Float16)(x3 - (float)h3)) << 16));
        *reinterpret_cast<uint2*>(&lds[0][r * AST + c4 * 4]) = hv;
        *reinterpret_cast<uint2*>(&lds[1][r * AST + c4 * 4]) = lv;
    }
    __syncthreads();

    // layer 1 (K=129, acc pre-seeded with z+gb1)
    KLOOP(S1, AIDX_L1, g1h, g1l)
    __syncthreads();
    WRITE_ACT_LDS()
    __syncthreads();
    // layer 2
    ACC_INIT_BIAS(gb2)
    KLOOP(S2, AIDX_SW, g2h, g2l)
    #pragma unroll
    for (int mt = 0; mt < 4; ++mt)
        #pragma unroll
        for (int nt = 0; nt < 4; ++nt)
            #pragma unroll
            for (int r = 0; r < 4; ++r)
                out[(size_t)(n0 + mt * 16 + 4 * g + r) * 256 + w * 64 + nt * 16 + cc] =
                    softplus_f(acc[mt][nt][r]);
}

// ---------------------------------------------------------------------------
// Kernel 5: mole_frac pass-through into the tail of the output tuple.
// ---------------------------------------------------------------------------
__global__ __launch_bounds__(256) void mf_copy_kernel(
    const float* __restrict__ mf, float* __restrict__ out) {
    int i = blockIdx.x * 256 + threadIdx.x;
    if (i < N_ROWS) out[(size_t)N_ROWS * 256 + i] = mf[i];
}

extern "C" void kernel_launch(void* const* d_in, const int* in_sizes, int n_in,
                              void* d_out, int out_size, void* d_ws, size_t ws_size,
                              hipStream_t stream) {
    const float* comp_emb = (const float*)d_in[0];
    const float* mf       = (const float*)d_in[1];
    const int*   seg      = (const int*)d_in[2];
    const float* iW1      = (const float*)d_in[3];
    const float* ib1      = (const float*)d_in[4];
    const float* iW2      = (const float*)d_in[5];
    const float* ib2      = (const float*)d_in[6];
    const float* gW1      = (const float*)d_in[7];
    const float* gb1      = (const float*)d_in[8];
    const float* gW2      = (const float*)d_in[9];
    const float* gb2      = (const float*)d_in[10];
    float* out = (float*)d_out;

    // workspace layout:
    //   seg_sum [M*132] f32 | counts [M] f32 | z [M*256] f32 | f16 weight packs
    float* seg_sum = (float*)d_ws;
    float* counts  = seg_sum + (size_t)M_SEG * SSTR;
    float* zbuf    = counts + M_SEG;
    unsigned short* pk  = (unsigned short*)(zbuf + (size_t)M_SEG * 256);
    unsigned short* i1h = pk;            unsigned short* i1l = i1h + 40960;
    unsigned short* i2h = i1l + 40960;   unsigned short* i2l = i2h + 65536;
    unsigned short* g1h = i2l + 65536;   unsigned short* g1l = g1h + 40960;
    unsigned short* gzh = g1l + 40960;   unsigned short* gzl = gzh + 65536;
    unsigned short* g2h = gzl + 65536;   unsigned short* g2l = g2h + 65536;

    hipMemsetAsync(d_ws, 0, ((size_t)M_SEG * SSTR + M_SEG) * sizeof(float), stream);

    // weight prepack (tiny)
    pack_w_kernel<<<20, 256, 0, stream>>>(iW1, 129, S1, i1h, i1l);
    pack_w_kernel<<<32, 256, 0, stream>>>(iW2, 256, S2, i2h, i2l);
    pack_w_kernel<<<20, 256, 0, stream>>>(gW1, 129, S1, g1h, g1l);              // emb|mf rows
    pack_w_kernel<<<32, 256, 0, stream>>>(gW1 + 129 * 256, 256, S2, gzh, gzl);  // ctx rows
    pack_w_kernel<<<32, 256, 0, stream>>>(gW2, 256, S2, g2h, g2l);

    {
        int total = N_ROWS * 130;
        segsum_kernel<<<(total + 255) / 256, 256, 0, stream>>>(comp_emb, mf, seg, seg_sum, counts);
    }
    mix_mfma_kernel<<<(M_SEG + 63) / 64, 256, 0, stream>>>(
        seg_sum, counts, i1h, i1l, ib1, i2h, i2l, ib2, gzh, gzl, gb1, zbuf);
    gate_mfma_kernel<<<N_ROWS / 64, 256, 0, stream>>>(
        comp_emb, mf, seg, zbuf, g1h, g1l, g2h, g2l, gb2, out);
    mf_copy_kernel<<<(N_ROWS + 255) / 256, 256, 0, stream>>>(mf, out);
}

// Round 2
// 1129.635 us; speedup vs baseline: 3.1866x; 1.1750x over previous
//
#include <hip/hip_runtime.h>

#define N_ROWS 400000
#define M_SEG  100000
#define EMB    128
#define SSTR   132      // seg_sum padded row stride (floats)
#define AST    168      // LDS A-stride (f16 elems) for K=160 (129 zero-padded)
#define S1     5        // K-steps for K=129 layers (padded to 160)
#define S2     8        // K-steps for K=256 layers

typedef _Float16 f16x8 __attribute__((ext_vector_type(8)));
typedef float    f32x4 __attribute__((ext_vector_type(4)));

__device__ __forceinline__ unsigned short h_bits(_Float16 h) {
    unsigned short u; __builtin_memcpy(&u, &h, 2); return u;
}
__device__ __forceinline__ float softplus_f(float x) {
    return fmaxf(x, 0.f) + __logf(1.f + __expf(-fabsf(x)));
}

// ---------------------------------------------------------------------------
// K-loop: 4 M-tiles x 2 N-tiles per wave (8 waves/block), f16 hi/lo 3-product.
// A-frag: row = lane&15 (cc), k = s*32 + (lane>>4)*8 + j   (16B ds_read)
// B-frag: prepacked so each lane's 8 elems are one coalesced dwordx4.
// C/D   : col = lane&15 (cc), row = 4*(lane>>4) + reg      (m89-verified)
// ---------------------------------------------------------------------------
#define KLOOP(STEPS, AIDX, BH, BL)                                                  \
  for (int s = 0; s < (STEPS); ++s) {                                               \
    f16x8 ah[4], al[4], bhv[2], blv[2];                                             \
    _Pragma("unroll")                                                               \
    for (int mt = 0; mt < 4; ++mt) {                                                \
      const int ai = (AIDX);                                                        \
      ah[mt] = *reinterpret_cast<const f16x8*>(&lds[0][ai]);                        \
      al[mt] = *reinterpret_cast<const f16x8*>(&lds[1][ai]);                        \
    }                                                                               \
    _Pragma("unroll")                                                               \
    for (int nt = 0; nt < 2; ++nt) {                                                \
      const size_t bo = (((size_t)s * 16 + w * 2 + nt) * 64 + lane) * 8;            \
      bhv[nt] = *reinterpret_cast<const f16x8*>(&(BH)[bo]);                         \
      blv[nt] = *reinterpret_cast<const f16x8*>(&(BL)[bo]);                         \
    }                                                                               \
    _Pragma("unroll")                                                               \
    for (int mt = 0; mt < 4; ++mt) {                                                \
      _Pragma("unroll")                                                             \
      for (int nt = 0; nt < 2; ++nt) {                                              \
        acc[mt][nt] = __builtin_amdgcn_mfma_f32_16x16x32_f16(ah[mt], bhv[nt], acc[mt][nt], 0, 0, 0); \
        acc[mt][nt] = __builtin_amdgcn_mfma_f32_16x16x32_f16(al[mt], bhv[nt], acc[mt][nt], 0, 0, 0); \
        acc[mt][nt] = __builtin_amdgcn_mfma_f32_16x16x32_f16(ah[mt], blv[nt], acc[mt][nt], 0, 0, 0); \
      }                                                                             \
    }                                                                               \
  }

// softplus(acc) -> hi/lo f16 planes in LDS, stride 256, XOR-swizzled.
#define WRITE_ACT_LDS()                                                   \
  _Pragma("unroll")                                                       \
  for (int mt = 0; mt < 4; ++mt)                                          \
    _Pragma("unroll")                                                     \
    for (int nt = 0; nt < 2; ++nt)                                        \
      _Pragma("unroll")                                                   \
      for (int r = 0; r < 4; ++r) {                                       \
        const float hv = softplus_f(acc[mt][nt][r]);                      \
        const int row = mt * 16 + 4 * g + r;                              \
        const int col = w * 32 + nt * 16 + cc;                            \
        const int si  = ((row * 256 + col) ^ ((row & 7) << 3));           \
        const _Float16 hh = (_Float16)hv;                                 \
        lds[0][si] = h_bits(hh);                                          \
        lds[1][si] = h_bits((_Float16)(hv - (float)hh));                  \
      }

#define ACC_INIT_BIAS(BPTR)                                   \
  _Pragma("unroll")                                           \
  for (int nt = 0; nt < 2; ++nt) {                            \
    const float b = (BPTR)[w * 32 + nt * 16 + cc];            \
    _Pragma("unroll")                                         \
    for (int mt = 0; mt < 4; ++mt)                            \
      _Pragma("unroll")                                       \
      for (int r = 0; r < 4; ++r) acc[mt][nt][r] = b;         \
  }

#define AIDX_L1 ((mt * 16 + cc) * AST + s * 32 + g * 8)
#define AIDX_SW ((((mt * 16 + cc) * 256 + s * 32 + g * 8)) ^ ((cc & 7) << 3))

// ---------------------------------------------------------------------------
// Segment CSR construction: count -> scan -> scatter -> gather-pool.
// ---------------------------------------------------------------------------
__global__ __launch_bounds__(256) void count_kernel(
    const int* __restrict__ seg, int* __restrict__ cnt) {
    int i = blockIdx.x * 256 + threadIdx.x;
    if (i < N_ROWS) atomicAdd(&cnt[seg[i]], 1);
}

// exclusive scan, 1024 elems/block; partials optional (block sums out)
__global__ __launch_bounds__(256) void scan_kernel(
    const int* __restrict__ cnt, int* __restrict__ excl,
    int* __restrict__ partials, int M) {
    __shared__ int tsum[256];
    const int t = threadIdx.x;
    const int b0 = blockIdx.x * 1024;
    int v[4]; int s = 0;
    #pragma unroll
    for (int j = 0; j < 4; ++j) {
        int idx = b0 + t * 4 + j;
        int c = (idx < M) ? cnt[idx] : 0;
        v[j] = s; s += c;
    }
    tsum[t] = s;
    __syncthreads();
    for (int off = 1; off < 256; off <<= 1) {
        int x = (t >= off) ? tsum[t - off] : 0;
        __syncthreads();
        tsum[t] += x;
        __syncthreads();
    }
    int tbase = (t > 0) ? tsum[t - 1] : 0;
    if (t == 255 && partials) partials[blockIdx.x] = tsum[255];
    #pragma unroll
    for (int j = 0; j < 4; ++j) {
        int idx = b0 + t * 4 + j;
        if (idx < M) excl[idx] = tbase + v[j];
    }
}

__global__ __launch_bounds__(256) void add_offsets_kernel(
    int* __restrict__ excl, const int* __restrict__ pex, int M) {
    int i = blockIdx.x * 256 + threadIdx.x;
    if (i < M) excl[i] += pex[i >> 10];
}

__global__ __launch_bounds__(256) void scatter_kernel(
    const int* __restrict__ seg, const int* __restrict__ base,
    int* __restrict__ cursor, int* __restrict__ rowids) {
    int i = blockIdx.x * 256 + threadIdx.x;
    if (i < N_ROWS) {
        int s = seg[i];
        int p = atomicAdd(&cursor[s], 1);
        rowids[base[s] + p] = i;
    }
}

// one wave per segment: lanes hold 2 emb cols; gather rows, sum, write.
__global__ __launch_bounds__(256) void pool_kernel(
    const float* __restrict__ comp_emb, const float* __restrict__ mf,
    const int* __restrict__ rowids, const int* __restrict__ base,
    float* __restrict__ seg_sum, float* __restrict__ countsf) {
    const int wid  = (blockIdx.x * 256 + threadIdx.x) >> 6;
    const int lane = threadIdx.x & 63;
    if (wid >= M_SEG) return;
    const int b = base[wid];
    const int e = (wid == M_SEG - 1) ? N_ROWS : base[wid + 1];
    float a0 = 0.f, a1 = 0.f, amf = 0.f;
    for (int j = b; j < e; ++j) {
        const int row = rowids[j];
        const float2 v = *reinterpret_cast<const float2*>(
            &comp_emb[(size_t)row * EMB + lane * 2]);
        a0 += v.x; a1 += v.y;
        if (lane == 0) amf += mf[row];
    }
    *reinterpret_cast<float2*>(&seg_sum[(size_t)wid * SSTR + lane * 2]) =
        make_float2(a0, a1);
    if (lane == 0) {
        seg_sum[(size_t)wid * SSTR + EMB] = amf;
        countsf[wid] = (float)(e - b);
    }
}

// ---------------------------------------------------------------------------
// Weight prepack into MFMA-fragment-ordered f16 hi/lo planes.
// ---------------------------------------------------------------------------
__global__ __launch_bounds__(256) void pack_w_kernel(
    const float* __restrict__ W, int K, int steps,
    unsigned short* __restrict__ ph, unsigned short* __restrict__ pl) {
    int idx = blockIdx.x * 256 + threadIdx.x;
    if (idx >= steps * 1024) return;
    int lane = idx & 63, t = idx >> 6, nt = t & 15, s = t >> 4;
    int c  = nt * 16 + (lane & 15);
    int k0 = s * 32 + (lane >> 4) * 8;
    unsigned short h[8], l[8];
    #pragma unroll
    for (int j = 0; j < 8; ++j) {
        int k = k0 + j;
        float v = (k < K) ? W[(size_t)k * 256 + c] : 0.f;
        _Float16 hh = (_Float16)v;
        h[j] = h_bits(hh);
        l[j] = h_bits((_Float16)(v - (float)hh));
    }
    __builtin_memcpy(&ph[(size_t)idx * 8], h, 16);
    __builtin_memcpy(&pl[(size_t)idx * 8], l, 16);
}

// ---------------------------------------------------------------------------
// Mixture pipeline, MFMA. 64 pooled rows/block, 512 thr (8 waves x 32 cols).
//   h   = softplus(pooled @ iW1 + ib1)        K=129
//   ctx = softplus(h @ iW2 + ib2)             K=256
//   z   = ctx @ gW1[129:,:] + gb1             K=256   (linear, stored f32)
// ---------------------------------------------------------------------------
__global__ __launch_bounds__(512, 4) void mix_mfma_kernel(
    const float* __restrict__ seg_sum, const float* __restrict__ counts,
    const unsigned short* __restrict__ i1h, const unsigned short* __restrict__ i1l,
    const float* __restrict__ ib1,
    const unsigned short* __restrict__ i2h, const unsigned short* __restrict__ i2l,
    const float* __restrict__ ib2,
    const unsigned short* __restrict__ gzh, const unsigned short* __restrict__ gzl,
    const float* __restrict__ gb1,
    float* __restrict__ z) {
    __shared__ unsigned short lds[2][64 * 256];   // 64 KB exactly
    const int m0  = blockIdx.x * 64;
    const int tid = threadIdx.x;
    const int w = tid >> 6, lane = tid & 63, g = lane >> 4, cc = lane & 15;

    // stage pooled rows (seg_sum/counts) as f16 hi/lo, stride AST
    for (int i = tid; i < 64 * 42; i += 512) {
        int r = i / 42, c4 = i - r * 42;
        int m = m0 + r;
        float x0 = 0.f, x1 = 0.f, x2 = 0.f, x3 = 0.f;
        if (m < M_SEG && c4 <= 32) {
            float inv = 1.f / fmaxf(counts[m], 1.f);
            if (c4 < 32) {
                const float4 v = *reinterpret_cast<const float4*>(&seg_sum[(size_t)m * SSTR + c4 * 4]);
                x0 = v.x * inv; x1 = v.y * inv; x2 = v.z * inv; x3 = v.w * inv;
            } else {
                x0 = seg_sum[(size_t)m * SSTR + EMB] * inv;
            }
        }
        _Float16 h0 = (_Float16)x0, h1 = (_Float16)x1, h2 = (_Float16)x2, h3 = (_Float16)x3;
        uint2 hv = make_uint2((unsigned)h_bits(h0) | ((unsigned)h_bits(h1) << 16),
                              (unsigned)h_bits(h2) | ((unsigned)h_bits(h3) << 16));
        uint2 lv = make_uint2((unsigned)h_bits((_Float16)(x0 - (float)h0)) |
                              ((unsigned)h_bits((_Float16)(x1 - (float)h1)) << 16),
                              (unsigned)h_bits((_Float16)(x2 - (float)h2)) |
                              ((unsigned)h_bits((_Float16)(x3 - (float)h3)) << 16));
        *reinterpret_cast<uint2*>(&lds[0][r * AST + c4 * 4]) = hv;
        *reinterpret_cast<uint2*>(&lds[1][r * AST + c4 * 4]) = lv;
    }
    __syncthreads();

    f32x4 acc[4][2];
    // layer 1
    ACC_INIT_BIAS(ib1)
    KLOOP(S1, AIDX_L1, i1h, i1l)
    __syncthreads();
    WRITE_ACT_LDS()
    __syncthreads();
    // layer 2
    ACC_INIT_BIAS(ib2)
    KLOOP(S2, AIDX_SW, i2h, i2l)
    __syncthreads();
    WRITE_ACT_LDS()          // ctx overwrites h (barrier above protects readers)
    __syncthreads();
    // layer 3: z = ctx @ gW1c + gb1 (linear)
    ACC_INIT_BIAS(gb1)
    KLOOP(S2, AIDX_SW, gzh, gzl)
    #pragma unroll
    for (int mt = 0; mt < 4; ++mt)
        #pragma unroll
        for (int nt = 0; nt < 2; ++nt)
            #pragma unroll
            for (int r = 0; r < 4; ++r) {
                int m = m0 + mt * 16 + 4 * g + r;
                if (m < M_SEG)
                    z[(size_t)m * 256 + w * 32 + nt * 16 + cc] = acc[mt][nt][r];
            }
}

// ---------------------------------------------------------------------------
// Gate MLP, MFMA. 64 rows/block, 512 thr (8 waves x 32 cols).
//   acc = z[seg[row]]  (ctx-part of layer1 + gb1, pre-folded)
//   g   = softplus(acc + [emb|mf] @ gW1[:129])     K=129
//   out = softplus(g @ gW2 + gb2)                  K=256
// ---------------------------------------------------------------------------
__global__ __launch_bounds__(512, 4) void gate_mfma_kernel(
    const float* __restrict__ comp_emb, const float* __restrict__ mf,
    const int* __restrict__ seg, const float* __restrict__ z,
    const unsigned short* __restrict__ g1h, const unsigned short* __restrict__ g1l,
    const unsigned short* __restrict__ g2h, const unsigned short* __restrict__ g2l,
    const float* __restrict__ gb2, float* __restrict__ out) {
    __shared__ unsigned short lds[2][64 * 256];   // 64 KB exactly
    const int n0  = blockIdx.x * 64;
    const int tid = threadIdx.x;
    const int w = tid >> 6, lane = tid & 63, g = lane >> 4, cc = lane & 15;

    // accumulator init: gather z[seg[row]] (issued early, overlaps staging)
    f32x4 acc[4][2];
    int rs[4][4];
    #pragma unroll
    for (int mt = 0; mt < 4; ++mt)
        #pragma unroll
        for (int r = 0; r < 4; ++r)
            rs[mt][r] = seg[n0 + mt * 16 + 4 * g + r];
    #pragma unroll
    for (int mt = 0; mt < 4; ++mt)
        #pragma unroll
        for (int nt = 0; nt < 2; ++nt)
            #pragma unroll
            for (int r = 0; r < 4; ++r)
                acc[mt][nt][r] = z[(size_t)rs[mt][r] * 256 + w * 32 + nt * 16 + cc];

    // stage [emb | mf | 0pad] as f16 hi/lo, stride AST
    for (int i = tid; i < 64 * 42; i += 512) {
        int r = i / 42, c4 = i - r * 42;
        int row = n0 + r;
        float x0 = 0.f, x1 = 0.f, x2 = 0.f, x3 = 0.f;
        if (c4 < 32) {
            const float4 v = *reinterpret_cast<const float4*>(&comp_emb[(size_t)row * EMB + c4 * 4]);
            x0 = v.x; x1 = v.y; x2 = v.z; x3 = v.w;
        } else if (c4 == 32) {
            x0 = mf[row];
        }
        _Float16 h0 = (_Float16)x0, h1 = (_Float16)x1, h2 = (_Float16)x2, h3 = (_Float16)x3;
        uint2 hv = make_uint2((unsigned)h_bits(h0) | ((unsigned)h_bits(h1) << 16),
                              (unsigned)h_bits(h2) | ((unsigned)h_bits(h3) << 16));
        uint2 lv = make_uint2((unsigned)h_bits((_Float16)(x0 - (float)h0)) |
                              ((unsigned)h_bits((_Float16)(x1 - (float)h1)) << 16),
                              (unsigned)h_bits((_Float16)(x2 - (float)h2)) |
                              ((unsigned)h_bits((_Float16)(x3 - (float)h3)) << 16));
        *reinterpret_cast<uint2*>(&lds[0][r * AST + c4 * 4]) = hv;
        *reinterpret_cast<uint2*>(&lds[1][r * AST + c4 * 4]) = lv;
    }
    __syncthreads();

    // layer 1 (K=129, acc pre-seeded with z+gb1)
    KLOOP(S1, AIDX_L1, g1h, g1l)
    __syncthreads();
    WRITE_ACT_LDS()
    __syncthreads();
    // layer 2
    ACC_INIT_BIAS(gb2)
    KLOOP(S2, AIDX_SW, g2h, g2l)
    #pragma unroll
    for (int mt = 0; mt < 4; ++mt)
        #pragma unroll
        for (int nt = 0; nt < 2; ++nt)
            #pragma unroll
            for (int r = 0; r < 4; ++r)
                out[(size_t)(n0 + mt * 16 + 4 * g + r) * 256 + w * 32 + nt * 16 + cc] =
                    softplus_f(acc[mt][nt][r]);
}

// ---------------------------------------------------------------------------
// mole_frac pass-through into the tail of the output tuple.
// ---------------------------------------------------------------------------
__global__ __launch_bounds__(256) void mf_copy_kernel(
    const float* __restrict__ mf, float* __restrict__ out) {
    int i = blockIdx.x * 256 + threadIdx.x;
    if (i < N_ROWS) out[(size_t)N_ROWS * 256 + i] = mf[i];
}

extern "C" void kernel_launch(void* const* d_in, const int* in_sizes, int n_in,
                              void* d_out, int out_size, void* d_ws, size_t ws_size,
                              hipStream_t stream) {
    const float* comp_emb = (const float*)d_in[0];
    const float* mf       = (const float*)d_in[1];
    const int*   seg      = (const int*)d_in[2];
    const float* iW1      = (const float*)d_in[3];
    const float* ib1      = (const float*)d_in[4];
    const float* iW2      = (const float*)d_in[5];
    const float* ib2      = (const float*)d_in[6];
    const float* gW1      = (const float*)d_in[7];
    const float* gb1      = (const float*)d_in[8];
    const float* gW2      = (const float*)d_in[9];
    const float* gb2      = (const float*)d_in[10];
    float* out = (float*)d_out;

    // workspace layout:
    //   seg_sum [M*132] f32 | countsf [M] f32 | z [M*256] f32 |
    //   f16 weight packs (557056 u16) | CSR ints
    float* seg_sum = (float*)d_ws;
    float* countsf = seg_sum + (size_t)M_SEG * SSTR;
    float* zbuf    = countsf + M_SEG;
    unsigned short* pk  = (unsigned short*)(zbuf + (size_t)M_SEG * 256);
    unsigned short* i1h = pk;            unsigned short* i1l = i1h + 40960;
    unsigned short* i2h = i1l + 40960;   unsigned short* i2l = i2h + 65536;
    unsigned short* g1h = i2l + 65536;   unsigned short* g1l = g1h + 40960;
    unsigned short* gzh = g1l + 40960;   unsigned short* gzl = gzh + 65536;
    unsigned short* g2h = gzl + 65536;   unsigned short* g2l = g2h + 65536;
    int* counts_i = (int*)(g2l + 65536);
    int* cursor   = counts_i + M_SEG;
    int* excl     = cursor + M_SEG;
    int* rowids   = excl + M_SEG;
    int* partials    = rowids + N_ROWS;
    int* partials_ex = partials + 128;

    // zero only the small atomic counters (counts_i + cursor, adjacent)
    hipMemsetAsync(counts_i, 0, 2 * (size_t)M_SEG * sizeof(int), stream);

    // weight prepack (tiny)
    pack_w_kernel<<<20, 256, 0, stream>>>(iW1, 129, S1, i1h, i1l);
    pack_w_kernel<<<32, 256, 0, stream>>>(iW2, 256, S2, i2h, i2l);
    pack_w_kernel<<<20, 256, 0, stream>>>(gW1, 129, S1, g1h, g1l);              // emb|mf rows
    pack_w_kernel<<<32, 256, 0, stream>>>(gW1 + 129 * 256, 256, S2, gzh, gzl);  // ctx rows
    pack_w_kernel<<<32, 256, 0, stream>>>(gW2, 256, S2, g2h, g2l);

    // CSR build: count -> scan(3) -> scatter -> pool
    const int nb_rows = (N_ROWS + 255) / 256;
    const int nb_scan = (M_SEG + 1023) / 1024;      // 98
    count_kernel<<<nb_rows, 256, 0, stream>>>(seg, counts_i);
    scan_kernel<<<nb_scan, 256, 0, stream>>>(counts_i, excl, partials, M_SEG);
    scan_kernel<<<1, 256, 0, stream>>>(partials, partials_ex, nullptr, nb_scan);
    add_offsets_kernel<<<(M_SEG + 255) / 256, 256, 0, stream>>>(excl, partials_ex, M_SEG);
    scatter_kernel<<<nb_rows, 256, 0, stream>>>(seg, excl, cursor, rowids);
    pool_kernel<<<(M_SEG * 64 + 255) / 256, 256, 0, stream>>>(
        comp_emb, mf, rowids, excl, seg_sum, countsf);

    mix_mfma_kernel<<<(M_SEG + 63) / 64, 512, 0, stream>>>(
        seg_sum, countsf, i1h, i1l, ib1, i2h, i2l, ib2, gzh, gzl, gb1, zbuf);
    gate_mfma_kernel<<<N_ROWS / 64, 512, 0, stream>>>(
        comp_emb, mf, seg, zbuf, g1h, g1l, g2h, g2l, gb2, out);
    mf_copy_kernel<<<(N_ROWS + 255) / 256, 256, 0, stream>>>(mf, out);
}

// Round 3
// 1012.702 us; speedup vs baseline: 3.5546x; 1.1155x over previous
//
#include <hip/hip_runtime.h>

#define N_ROWS 400000
#define M_SEG  100000
#define EMB    128
#define SSTR   132      // seg_sum padded row stride (floats)
#define AST    168      // LDS A-stride (f16 elems) for K=160 (129 zero-padded)
#define S1     5        // K-steps for K=129 layers (padded to 160)
#define S2     8        // K-steps for K=256 layers

typedef _Float16 f16x8 __attribute__((ext_vector_type(8)));
typedef float    f32x4 __attribute__((ext_vector_type(4)));

__device__ __forceinline__ unsigned short h_bits(_Float16 h) {
    unsigned short u; __builtin_memcpy(&u, &h, 2); return u;
}
__device__ __forceinline__ float f_from_bits(unsigned short u) {
    _Float16 h; __builtin_memcpy(&h, &u, 2); return (float)h;
}
__device__ __forceinline__ float softplus_f(float x) {
    return fmaxf(x, 0.f) + __logf(1.f + __expf(-fabsf(x)));
}

// ---------------------------------------------------------------------------
// K-loop: 4 M-tiles x 2 N-tiles per wave (8 waves/block), single f16 product.
// A-frag: row = lane&15 (cc), k = s*32 + (lane>>4)*8 + j   (16B ds_read)
// B-frag: prepacked so each lane's 8 elems are one coalesced dwordx4.
// C/D   : col = lane&15 (cc), row = 4*(lane>>4) + reg      (verified r1/r2)
// ---------------------------------------------------------------------------
#define KLOOP(STEPS, AIDX, BH)                                                      \
  for (int s = 0; s < (STEPS); ++s) {                                               \
    f16x8 ah[4], bhv[2];                                                            \
    _Pragma("unroll")                                                               \
    for (int mt = 0; mt < 4; ++mt) {                                                \
      const int ai = (AIDX);                                                        \
      ah[mt] = *reinterpret_cast<const f16x8*>(&lds[ai]);                           \
    }                                                                               \
    _Pragma("unroll")                                                               \
    for (int nt = 0; nt < 2; ++nt) {                                                \
      const size_t bo = (((size_t)s * 16 + w * 2 + nt) * 64 + lane) * 8;            \
      bhv[nt] = *reinterpret_cast<const f16x8*>(&(BH)[bo]);                         \
    }                                                                               \
    _Pragma("unroll")                                                               \
    for (int mt = 0; mt < 4; ++mt) {                                                \
      _Pragma("unroll")                                                             \
      for (int nt = 0; nt < 2; ++nt) {                                              \
        acc[mt][nt] = __builtin_amdgcn_mfma_f32_16x16x32_f16(ah[mt], bhv[nt], acc[mt][nt], 0, 0, 0); \
      }                                                                             \
    }                                                                               \
  }

// softplus(acc) -> f16 plane in LDS, stride 256, XOR-swizzled (G4).
#define WRITE_ACT_LDS()                                                   \
  _Pragma("unroll")                                                       \
  for (int mt = 0; mt < 4; ++mt)                                          \
    _Pragma("unroll")                                                     \
    for (int nt = 0; nt < 2; ++nt)                                        \
      _Pragma("unroll")                                                   \
      for (int r = 0; r < 4; ++r) {                                       \
        const float hv = softplus_f(acc[mt][nt][r]);                      \
        const int row = mt * 16 + 4 * g + r;                              \
        const int col = w * 32 + nt * 16 + cc;                            \
        const int si  = ((row * 256 + col) ^ ((row & 7) << 3));           \
        lds[si] = h_bits((_Float16)hv);                                   \
      }

#define ACC_INIT_BIAS(BPTR)                                   \
  _Pragma("unroll")                                           \
  for (int nt = 0; nt < 2; ++nt) {                            \
    const float b = (BPTR)[w * 32 + nt * 16 + cc];            \
    _Pragma("unroll")                                         \
    for (int mt = 0; mt < 4; ++mt)                            \
      _Pragma("unroll")                                       \
      for (int r = 0; r < 4; ++r) acc[mt][nt][r] = b;         \
  }

#define AIDX_L1 ((mt * 16 + cc) * AST + s * 32 + g * 8)
#define AIDX_SW ((((mt * 16 + cc) * 256 + s * 32 + g * 8)) ^ ((cc & 7) << 3))

// ---------------------------------------------------------------------------
// Segment CSR construction: count -> scan -> scatter -> gather-pool.
// ---------------------------------------------------------------------------
__global__ __launch_bounds__(256) void count_kernel(
    const int* __restrict__ seg, int* __restrict__ cnt) {
    int i = blockIdx.x * 256 + threadIdx.x;
    if (i < N_ROWS) atomicAdd(&cnt[seg[i]], 1);
}

// exclusive scan, 1024 elems/block; partials optional (block sums out)
__global__ __launch_bounds__(256) void scan_kernel(
    const int* __restrict__ cnt, int* __restrict__ excl,
    int* __restrict__ partials, int M) {
    __shared__ int tsum[256];
    const int t = threadIdx.x;
    const int b0 = blockIdx.x * 1024;
    int v[4]; int s = 0;
    #pragma unroll
    for (int j = 0; j < 4; ++j) {
        int idx = b0 + t * 4 + j;
        int c = (idx < M) ? cnt[idx] : 0;
        v[j] = s; s += c;
    }
    tsum[t] = s;
    __syncthreads();
    for (int off = 1; off < 256; off <<= 1) {
        int x = (t >= off) ? tsum[t - off] : 0;
        __syncthreads();
        tsum[t] += x;
        __syncthreads();
    }
    int tbase = (t > 0) ? tsum[t - 1] : 0;
    if (t == 255 && partials) partials[blockIdx.x] = tsum[255];
    #pragma unroll
    for (int j = 0; j < 4; ++j) {
        int idx = b0 + t * 4 + j;
        if (idx < M) excl[idx] = tbase + v[j];
    }
}

__global__ __launch_bounds__(256) void add_offsets_kernel(
    int* __restrict__ excl, const int* __restrict__ pex, int M) {
    int i = blockIdx.x * 256 + threadIdx.x;
    if (i < M) excl[i] += pex[i >> 10];
}

__global__ __launch_bounds__(256) void scatter_kernel(
    const int* __restrict__ seg, const int* __restrict__ base,
    int* __restrict__ cursor, int* __restrict__ rowids) {
    int i = blockIdx.x * 256 + threadIdx.x;
    if (i < N_ROWS) {
        int s = seg[i];
        int p = atomicAdd(&cursor[s], 1);
        rowids[base[s] + p] = i;
    }
}

// one wave per segment: lanes hold 2 emb cols; gather rows, sum, write.
__global__ __launch_bounds__(256) void pool_kernel(
    const float* __restrict__ comp_emb, const float* __restrict__ mf,
    const int* __restrict__ rowids, const int* __restrict__ base,
    float* __restrict__ seg_sum, float* __restrict__ countsf) {
    const int wid  = (blockIdx.x * 256 + threadIdx.x) >> 6;
    const int lane = threadIdx.x & 63;
    if (wid >= M_SEG) return;
    const int b = base[wid];
    const int e = (wid == M_SEG - 1) ? N_ROWS : base[wid + 1];
    float a0 = 0.f, a1 = 0.f, amf = 0.f;
    for (int j = b; j < e; ++j) {
        const int row = rowids[j];
        const float2 v = *reinterpret_cast<const float2*>(
            &comp_emb[(size_t)row * EMB + lane * 2]);
        a0 += v.x; a1 += v.y;
        if (lane == 0) amf += mf[row];
    }
    *reinterpret_cast<float2*>(&seg_sum[(size_t)wid * SSTR + lane * 2]) =
        make_float2(a0, a1);
    if (lane == 0) {
        seg_sum[(size_t)wid * SSTR + EMB] = amf;
        countsf[wid] = (float)(e - b);
    }
}

// ---------------------------------------------------------------------------
// Weight prepack into MFMA-fragment-ordered f16 plane (hi only).
// ---------------------------------------------------------------------------
__global__ __launch_bounds__(256) void pack_w_kernel(
    const float* __restrict__ W, int K, int steps,
    unsigned short* __restrict__ ph) {
    int idx = blockIdx.x * 256 + threadIdx.x;
    if (idx >= steps * 1024) return;
    int lane = idx & 63, t = idx >> 6, nt = t & 15, s = t >> 4;
    int c  = nt * 16 + (lane & 15);
    int k0 = s * 32 + (lane >> 4) * 8;
    unsigned short h[8];
    #pragma unroll
    for (int j = 0; j < 8; ++j) {
        int k = k0 + j;
        float v = (k < K) ? W[(size_t)k * 256 + c] : 0.f;
        h[j] = h_bits((_Float16)v);
    }
    __builtin_memcpy(&ph[(size_t)idx * 8], h, 16);
}

// ---------------------------------------------------------------------------
// Mixture pipeline, MFMA. 64 pooled rows/block, 512 thr (8 waves x 32 cols).
//   h   = softplus(pooled @ iW1 + ib1)        K=129
//   ctx = softplus(h @ iW2 + ib2)             K=256
//   z   = ctx @ gW1[129:,:] + gb1             K=256   (linear, stored f16)
// ---------------------------------------------------------------------------
__global__ __launch_bounds__(512, 6) void mix_mfma_kernel(
    const float* __restrict__ seg_sum, const float* __restrict__ counts,
    const unsigned short* __restrict__ i1h, const float* __restrict__ ib1,
    const unsigned short* __restrict__ i2h, const float* __restrict__ ib2,
    const unsigned short* __restrict__ gzh, const float* __restrict__ gb1,
    unsigned short* __restrict__ zh) {
    __shared__ unsigned short lds[64 * 256];   // 32 KB
    const int m0  = blockIdx.x * 64;
    const int tid = threadIdx.x;
    const int w = tid >> 6, lane = tid & 63, g = lane >> 4, cc = lane & 15;

    // stage pooled rows (seg_sum/counts) as f16, stride AST
    for (int i = tid; i < 64 * 42; i += 512) {
        int r = i / 42, c4 = i - r * 42;
        int m = m0 + r;
        float x0 = 0.f, x1 = 0.f, x2 = 0.f, x3 = 0.f;
        if (m < M_SEG && c4 <= 32) {
            float inv = 1.f / fmaxf(counts[m], 1.f);
            if (c4 < 32) {
                const float4 v = *reinterpret_cast<const float4*>(&seg_sum[(size_t)m * SSTR + c4 * 4]);
                x0 = v.x * inv; x1 = v.y * inv; x2 = v.z * inv; x3 = v.w * inv;
            } else {
                x0 = seg_sum[(size_t)m * SSTR + EMB] * inv;
            }
        }
        uint2 hv = make_uint2((unsigned)h_bits((_Float16)x0) | ((unsigned)h_bits((_Float16)x1) << 16),
                              (unsigned)h_bits((_Float16)x2) | ((unsigned)h_bits((_Float16)x3) << 16));
        *reinterpret_cast<uint2*>(&lds[r * AST + c4 * 4]) = hv;
    }
    __syncthreads();

    f32x4 acc[4][2];
    // layer 1
    ACC_INIT_BIAS(ib1)
    KLOOP(S1, AIDX_L1, i1h)
    __syncthreads();
    WRITE_ACT_LDS()
    __syncthreads();
    // layer 2
    ACC_INIT_BIAS(ib2)
    KLOOP(S2, AIDX_SW, i2h)
    __syncthreads();
    WRITE_ACT_LDS()          // ctx overwrites h (barrier above protects readers)
    __syncthreads();
    // layer 3: z = ctx @ gW1c + gb1 (linear, f16 out)
    ACC_INIT_BIAS(gb1)
    KLOOP(S2, AIDX_SW, gzh)
    #pragma unroll
    for (int mt = 0; mt < 4; ++mt)
        #pragma unroll
        for (int nt = 0; nt < 2; ++nt)
            #pragma unroll
            for (int r = 0; r < 4; ++r) {
                int m = m0 + mt * 16 + 4 * g + r;
                if (m < M_SEG)
                    zh[(size_t)m * 256 + w * 32 + nt * 16 + cc] =
                        h_bits((_Float16)acc[mt][nt][r]);
            }
}

// ---------------------------------------------------------------------------
// Gate MLP, MFMA. 64 rows/block, 512 thr (8 waves x 32 cols).
//   acc = z[seg[row]]  (ctx-part of layer1 + gb1, pre-folded)
//   g   = softplus(acc + [emb|mf] @ gW1[:129])     K=129
//   out = softplus(g @ gW2 + gb2)                  K=256
// ---------------------------------------------------------------------------
__global__ __launch_bounds__(512, 6) void gate_mfma_kernel(
    const float* __restrict__ comp_emb, const float* __restrict__ mf,
    const int* __restrict__ seg, const unsigned short* __restrict__ zh,
    const unsigned short* __restrict__ g1h, const unsigned short* __restrict__ g2h,
    const float* __restrict__ gb2, float* __restrict__ out) {
    __shared__ unsigned short lds[64 * 256];   // 32 KB
    const int n0  = blockIdx.x * 64;
    const int tid = threadIdx.x;
    const int w = tid >> 6, lane = tid & 63, g = lane >> 4, cc = lane & 15;

    // accumulator init: gather z[seg[row]] (issued early, overlaps staging)
    f32x4 acc[4][2];
    int rs[4][4];
    #pragma unroll
    for (int mt = 0; mt < 4; ++mt)
        #pragma unroll
        for (int r = 0; r < 4; ++r)
            rs[mt][r] = seg[n0 + mt * 16 + 4 * g + r];
    #pragma unroll
    for (int mt = 0; mt < 4; ++mt)
        #pragma unroll
        for (int nt = 0; nt < 2; ++nt)
            #pragma unroll
            for (int r = 0; r < 4; ++r)
                acc[mt][nt][r] = f_from_bits(
                    zh[(size_t)rs[mt][r] * 256 + w * 32 + nt * 16 + cc]);

    // stage [emb | mf | 0pad] as f16, stride AST
    for (int i = tid; i < 64 * 42; i += 512) {
        int r = i / 42, c4 = i - r * 42;
        int row = n0 + r;
        float x0 = 0.f, x1 = 0.f, x2 = 0.f, x3 = 0.f;
        if (c4 < 32) {
            const float4 v = *reinterpret_cast<const float4*>(&comp_emb[(size_t)row * EMB + c4 * 4]);
            x0 = v.x; x1 = v.y; x2 = v.z; x3 = v.w;
        } else if (c4 == 32) {
            x0 = mf[row];
        }
        uint2 hv = make_uint2((unsigned)h_bits((_Float16)x0) | ((unsigned)h_bits((_Float16)x1) << 16),
                              (unsigned)h_bits((_Float16)x2) | ((unsigned)h_bits((_Float16)x3) << 16));
        *reinterpret_cast<uint2*>(&lds[r * AST + c4 * 4]) = hv;
    }
    __syncthreads();

    // layer 1 (K=129, acc pre-seeded with z+gb1)
    KLOOP(S1, AIDX_L1, g1h)
    __syncthreads();
    WRITE_ACT_LDS()
    __syncthreads();
    // layer 2
    ACC_INIT_BIAS(gb2)
    KLOOP(S2, AIDX_SW, g2h)
    #pragma unroll
    for (int mt = 0; mt < 4; ++mt)
        #pragma unroll
        for (int nt = 0; nt < 2; ++nt)
            #pragma unroll
            for (int r = 0; r < 4; ++r)
                out[(size_t)(n0 + mt * 16 + 4 * g + r) * 256 + w * 32 + nt * 16 + cc] =
                    softplus_f(acc[mt][nt][r]);
}

// ---------------------------------------------------------------------------
// mole_frac pass-through into the tail of the output tuple.
// ---------------------------------------------------------------------------
__global__ __launch_bounds__(256) void mf_copy_kernel(
    const float* __restrict__ mf, float* __restrict__ out) {
    int i = blockIdx.x * 256 + threadIdx.x;
    if (i < N_ROWS) out[(size_t)N_ROWS * 256 + i] = mf[i];
}

extern "C" void kernel_launch(void* const* d_in, const int* in_sizes, int n_in,
                              void* d_out, int out_size, void* d_ws, size_t ws_size,
                              hipStream_t stream) {
    const float* comp_emb = (const float*)d_in[0];
    const float* mf       = (const float*)d_in[1];
    const int*   seg      = (const int*)d_in[2];
    const float* iW1      = (const float*)d_in[3];
    const float* ib1      = (const float*)d_in[4];
    const float* iW2      = (const float*)d_in[5];
    const float* ib2      = (const float*)d_in[6];
    const float* gW1      = (const float*)d_in[7];
    const float* gb1      = (const float*)d_in[8];
    const float* gW2      = (const float*)d_in[9];
    const float* gb2      = (const float*)d_in[10];
    float* out = (float*)d_out;

    // workspace layout:
    //   seg_sum [M*132] f32 | countsf [M] f32 | zh [M*256] u16 |
    //   f16 weight packs (278528 u16) | CSR ints
    float* seg_sum = (float*)d_ws;
    float* countsf = seg_sum + (size_t)M_SEG * SSTR;
    unsigned short* zh = (unsigned short*)(countsf + M_SEG);
    unsigned short* i1h = zh + (size_t)M_SEG * 256;
    unsigned short* i2h = i1h + 40960;
    unsigned short* g1h = i2h + 65536;
    unsigned short* gzh = g1h + 40960;
    unsigned short* g2h = gzh + 65536;
    int* counts_i = (int*)(g2h + 65536);
    int* cursor   = counts_i + M_SEG;
    int* excl     = cursor + M_SEG;
    int* rowids   = excl + M_SEG;
    int* partials    = rowids + N_ROWS;
    int* partials_ex = partials + 128;

    // zero only the small atomic counters (counts_i + cursor, adjacent)
    hipMemsetAsync(counts_i, 0, 2 * (size_t)M_SEG * sizeof(int), stream);

    // weight prepack (tiny)
    pack_w_kernel<<<20, 256, 0, stream>>>(iW1, 129, S1, i1h);
    pack_w_kernel<<<32, 256, 0, stream>>>(iW2, 256, S2, i2h);
    pack_w_kernel<<<20, 256, 0, stream>>>(gW1, 129, S1, g1h);              // emb|mf rows
    pack_w_kernel<<<32, 256, 0, stream>>>(gW1 + 129 * 256, 256, S2, gzh);  // ctx rows
    pack_w_kernel<<<32, 256, 0, stream>>>(gW2, 256, S2, g2h);

    // CSR build: count -> scan(3) -> scatter -> pool
    const int nb_rows = (N_ROWS + 255) / 256;
    const int nb_scan = (M_SEG + 1023) / 1024;      // 98
    count_kernel<<<nb_rows, 256, 0, stream>>>(seg, counts_i);
    scan_kernel<<<nb_scan, 256, 0, stream>>>(counts_i, excl, partials, M_SEG);
    scan_kernel<<<1, 256, 0, stream>>>(partials, partials_ex, nullptr, nb_scan);
    add_offsets_kernel<<<(M_SEG + 255) / 256, 256, 0, stream>>>(excl, partials_ex, M_SEG);
    scatter_kernel<<<nb_rows, 256, 0, stream>>>(seg, excl, cursor, rowids);
    pool_kernel<<<(M_SEG * 64 + 255) / 256, 256, 0, stream>>>(
        comp_emb, mf, rowids, excl, seg_sum, countsf);

    mix_mfma_kernel<<<(M_SEG + 63) / 64, 512, 0, stream>>>(
        seg_sum, countsf, i1h, ib1, i2h, ib2, gzh, gb1, zh);
    gate_mfma_kernel<<<N_ROWS / 64, 512, 0, stream>>>(
        comp_emb, mf, seg, zh, g1h, g2h, gb2, out);
    mf_copy_kernel<<<(N_ROWS + 255) / 256, 256, 0, stream>>>(mf, out);
}

// Round 4
// 997.101 us; speedup vs baseline: 3.6102x; 1.0156x over previous
//
#include <hip/hip_runtime.h>

#define N_ROWS 400000
#define M_SEG  100000
#define EMB    128
#define AST    168      // LDS A-stride (f16 elems) for K=160 (129 zero-padded)
#define S1     5        // K-steps for K=129 layers (padded to 160)
#define S2     8        // K-steps for K=256 layers

typedef _Float16 f16x8 __attribute__((ext_vector_type(8)));
typedef float    f32x4 __attribute__((ext_vector_type(4)));

__device__ __forceinline__ unsigned short h_bits(_Float16 h) {
    unsigned short u; __builtin_memcpy(&u, &h, 2); return u;
}
__device__ __forceinline__ float f_from_bits(unsigned short u) {
    _Float16 h; __builtin_memcpy(&h, &u, 2); return (float)h;
}
__device__ __forceinline__ float softplus_f(float x) {
    return fmaxf(x, 0.f) + __logf(1.f + __expf(-fabsf(x)));
}

// ---------------------------------------------------------------------------
// Pipelined K-loop: 4 M-tiles x 2 N-tiles per wave (8 waves/block), f16 MFMA.
// 2-deep B prefetch: next step's B-frag global loads issue before this step's
// MFMAs, so L2 latency hides under compute (fully unrolled, STEPS <= 8).
// A-frag: row = lane&15 (cc), k = s*32 + (lane>>4)*8 + j   (16B ds_read)
// B-frag: prepacked so each lane's 8 elems are one coalesced dwordx4.
// C/D   : col = lane&15 (cc), row = 4*(lane>>4) + reg      (verified r1-r3)
// ---------------------------------------------------------------------------
#define KLOOP_P(STEPS, AIDX, BH)                                                    \
  {                                                                                 \
    f16x8 bcur[2], bnxt[2];                                                         \
    _Pragma("unroll")                                                               \
    for (int nt = 0; nt < 2; ++nt)                                                  \
      bcur[nt] = *reinterpret_cast<const f16x8*>(&(BH)[((size_t)(w * 2 + nt) * 64 + lane) * 8]); \
    _Pragma("unroll")                                                               \
    for (int s = 0; s < (STEPS); ++s) {                                             \
      if (s + 1 < (STEPS)) {                                                        \
        _Pragma("unroll")                                                           \
        for (int nt = 0; nt < 2; ++nt)                                              \
          bnxt[nt] = *reinterpret_cast<const f16x8*>(                               \
              &(BH)[(((size_t)(s + 1) * 16 + w * 2 + nt) * 64 + lane) * 8]);        \
      }                                                                             \
      f16x8 ah[4];                                                                  \
      _Pragma("unroll")                                                             \
      for (int mt = 0; mt < 4; ++mt) {                                              \
        const int ai = (AIDX);                                                      \
        ah[mt] = *reinterpret_cast<const f16x8*>(&lds[ai]);                         \
      }                                                                             \
      _Pragma("unroll")                                                             \
      for (int mt = 0; mt < 4; ++mt)                                                \
        _Pragma("unroll")                                                           \
        for (int nt = 0; nt < 2; ++nt)                                              \
          acc[mt][nt] = __builtin_amdgcn_mfma_f32_16x16x32_f16(ah[mt], bcur[nt], acc[mt][nt], 0, 0, 0); \
      bcur[0] = bnxt[0]; bcur[1] = bnxt[1];                                         \
    }                                                                               \
  }

// softplus(acc) -> f16 plane in LDS, stride 256, XOR-swizzled (G4).
#define WRITE_ACT_LDS()                                                   \
  _Pragma("unroll")                                                       \
  for (int mt = 0; mt < 4; ++mt)                                          \
    _Pragma("unroll")                                                     \
    for (int nt = 0; nt < 2; ++nt)                                        \
      _Pragma("unroll")                                                   \
      for (int r = 0; r < 4; ++r) {                                       \
        const float hv = softplus_f(acc[mt][nt][r]);                      \
        const int row = mt * 16 + 4 * g + r;                              \
        const int col = w * 32 + nt * 16 + cc;                            \
        const int si  = ((row * 256 + col) ^ ((row & 7) << 3));           \
        lds[si] = h_bits((_Float16)hv);                                   \
      }

#define ACC_INIT_BIAS(BPTR)                                   \
  _Pragma("unroll")                                           \
  for (int nt = 0; nt < 2; ++nt) {                            \
    const float b = (BPTR)[w * 32 + nt * 16 + cc];            \
    _Pragma("unroll")                                         \
    for (int mt = 0; mt < 4; ++mt)                            \
      _Pragma("unroll")                                       \
      for (int r = 0; r < 4; ++r) acc[mt][nt][r] = b;         \
  }

#define AIDX_L1 ((mt * 16 + cc) * AST + s * 32 + g * 8)
#define AIDX_SW ((((mt * 16 + cc) * 256 + s * 32 + g * 8)) ^ ((cc & 7) << 3))

// ---------------------------------------------------------------------------
// Segment CSR construction: count -> scan -> scatter.
// ---------------------------------------------------------------------------
__global__ __launch_bounds__(256) void count_kernel(
    const int* __restrict__ seg, int* __restrict__ cnt) {
    int i = blockIdx.x * 256 + threadIdx.x;
    if (i < N_ROWS) atomicAdd(&cnt[seg[i]], 1);
}

// exclusive scan, 1024 elems/block; partials optional (block sums out)
__global__ __launch_bounds__(256) void scan_kernel(
    const int* __restrict__ cnt, int* __restrict__ excl,
    int* __restrict__ partials, int M) {
    __shared__ int tsum[256];
    const int t = threadIdx.x;
    const int b0 = blockIdx.x * 1024;
    int v[4]; int s = 0;
    #pragma unroll
    for (int j = 0; j < 4; ++j) {
        int idx = b0 + t * 4 + j;
        int c = (idx < M) ? cnt[idx] : 0;
        v[j] = s; s += c;
    }
    tsum[t] = s;
    __syncthreads();
    for (int off = 1; off < 256; off <<= 1) {
        int x = (t >= off) ? tsum[t - off] : 0;
        __syncthreads();
        tsum[t] += x;
        __syncthreads();
    }
    int tbase = (t > 0) ? tsum[t - 1] : 0;
    if (t == 255 && partials) partials[blockIdx.x] = tsum[255];
    #pragma unroll
    for (int j = 0; j < 4; ++j) {
        int idx = b0 + t * 4 + j;
        if (idx < M) excl[idx] = tbase + v[j];
    }
}

__global__ __launch_bounds__(256) void add_offsets_kernel(
    int* __restrict__ excl, const int* __restrict__ pex, int M) {
    int i = blockIdx.x * 256 + threadIdx.x;
    if (i < M) excl[i] += pex[i >> 10];
}

__global__ __launch_bounds__(256) void scatter_kernel(
    const int* __restrict__ seg, const int* __restrict__ base,
    int* __restrict__ cursor, int* __restrict__ rowids) {
    int i = blockIdx.x * 256 + threadIdx.x;
    if (i < N_ROWS) {
        int s = seg[i];
        int p = atomicAdd(&cursor[s], 1);
        rowids[base[s] + p] = i;
    }
}

// ---------------------------------------------------------------------------
// Weight prepack into MFMA-fragment-ordered f16 plane.
// ---------------------------------------------------------------------------
__global__ __launch_bounds__(256) void pack_w_kernel(
    const float* __restrict__ W, int K, int steps,
    unsigned short* __restrict__ ph) {
    int idx = blockIdx.x * 256 + threadIdx.x;
    if (idx >= steps * 1024) return;
    int lane = idx & 63, t = idx >> 6, nt = t & 15, s = t >> 4;
    int c  = nt * 16 + (lane & 15);
    int k0 = s * 32 + (lane >> 4) * 8;
    unsigned short h[8];
    #pragma unroll
    for (int j = 0; j < 8; ++j) {
        int k = k0 + j;
        float v = (k < K) ? W[(size_t)k * 256 + c] : 0.f;
        h[j] = h_bits((_Float16)v);
    }
    __builtin_memcpy(&ph[(size_t)idx * 8], h, 16);
}

// ---------------------------------------------------------------------------
// Mixture pipeline, MFMA, with fused CSR pooling. 64 segments/block,
// 512 thr (8 waves). Staging: wave w pools segments w*8..w*8+7 directly
// from comp_emb rows via CSR (coalesced 512B row gathers) into LDS f16.
//   h   = softplus(pooled @ iW1 + ib1)        K=129
//   ctx = softplus(h @ iW2 + ib2)             K=256
//   z   = ctx @ gW1[129:,:] + gb1             K=256   (linear, stored f16)
// ---------------------------------------------------------------------------
__global__ __launch_bounds__(512, 6) void mix_mfma_kernel(
    const float* __restrict__ comp_emb, const float* __restrict__ mf,
    const int* __restrict__ rowids, const int* __restrict__ excl,
    const unsigned short* __restrict__ i1h, const float* __restrict__ ib1,
    const unsigned short* __restrict__ i2h, const float* __restrict__ ib2,
    const unsigned short* __restrict__ gzh, const float* __restrict__ gb1,
    unsigned short* __restrict__ zh) {
    __shared__ unsigned short lds[64 * 256];   // 32 KB
    const int m0  = blockIdx.x * 64;
    const int tid = threadIdx.x;
    const int w = tid >> 6, lane = tid & 63, g = lane >> 4, cc = lane & 15;

    // pool 8 segments per wave straight from CSR into LDS (f16, stride AST)
    for (int q = 0; q < 8; ++q) {
        const int ml = w * 8 + q;
        const int m  = m0 + ml;
        int b = 0, e = 0;
        if (m < M_SEG) {
            b = excl[m];
            e = (m == M_SEG - 1) ? N_ROWS : excl[m + 1];
        }
        float a0 = 0.f, a1 = 0.f, amf = 0.f;
        for (int j = b; j < e; ++j) {
            const int row = rowids[j];
            const float2 v = *reinterpret_cast<const float2*>(
                &comp_emb[(size_t)row * EMB + lane * 2]);
            a0 += v.x; a1 += v.y;
            if (lane == 0) amf += mf[row];
        }
        const float inv = 1.f / fmaxf((float)(e - b), 1.f);
        unsigned u = (unsigned)h_bits((_Float16)(a0 * inv)) |
                     ((unsigned)h_bits((_Float16)(a1 * inv)) << 16);
        *reinterpret_cast<unsigned*>(&lds[ml * AST + lane * 2]) = u;
        if (lane == 0) {
            unsigned um = (unsigned)h_bits((_Float16)(amf * inv));  // [mf | 0]
            *reinterpret_cast<unsigned*>(&lds[ml * AST + 128]) = um;
        } else if (lane <= 15) {
            *reinterpret_cast<unsigned*>(&lds[ml * AST + 128 + lane * 2]) = 0u;
        }
    }
    __syncthreads();

    f32x4 acc[4][2];
    // layer 1
    ACC_INIT_BIAS(ib1)
    KLOOP_P(S1, AIDX_L1, i1h)
    __syncthreads();
    WRITE_ACT_LDS()
    __syncthreads();
    // layer 2
    ACC_INIT_BIAS(ib2)
    KLOOP_P(S2, AIDX_SW, i2h)
    __syncthreads();
    WRITE_ACT_LDS()          // ctx overwrites h (barrier above protects readers)
    __syncthreads();
    // layer 3: z = ctx @ gW1c + gb1 (linear, f16 out)
    ACC_INIT_BIAS(gb1)
    KLOOP_P(S2, AIDX_SW, gzh)
    #pragma unroll
    for (int mt = 0; mt < 4; ++mt)
        #pragma unroll
        for (int nt = 0; nt < 2; ++nt)
            #pragma unroll
            for (int r = 0; r < 4; ++r) {
                int m = m0 + mt * 16 + 4 * g + r;
                if (m < M_SEG)
                    zh[(size_t)m * 256 + w * 32 + nt * 16 + cc] =
                        h_bits((_Float16)acc[mt][nt][r]);
            }
}

// ---------------------------------------------------------------------------
// Gate MLP, MFMA. 64 rows/block, 512 thr (8 waves x 32 cols).
//   acc = z[seg[row]]  (ctx-part of layer1 + gb1, pre-folded)
//   g   = softplus(acc + [emb|mf] @ gW1[:129])     K=129
//   out = softplus(g @ gW2 + gb2)                  K=256
// Fused: mole_frac tail copy for this block's 64 rows.
// ---------------------------------------------------------------------------
__global__ __launch_bounds__(512, 6) void gate_mfma_kernel(
    const float* __restrict__ comp_emb, const float* __restrict__ mf,
    const int* __restrict__ seg, const unsigned short* __restrict__ zh,
    const unsigned short* __restrict__ g1h, const unsigned short* __restrict__ g2h,
    const float* __restrict__ gb2, float* __restrict__ out) {
    __shared__ unsigned short lds[64 * 256];   // 32 KB
    const int n0  = blockIdx.x * 64;
    const int tid = threadIdx.x;
    const int w = tid >> 6, lane = tid & 63, g = lane >> 4, cc = lane & 15;

    // accumulator init: gather z[seg[row]] (issued early, overlaps staging)
    f32x4 acc[4][2];
    int rs[4][4];
    #pragma unroll
    for (int mt = 0; mt < 4; ++mt)
        #pragma unroll
        for (int r = 0; r < 4; ++r)
            rs[mt][r] = seg[n0 + mt * 16 + 4 * g + r];
    #pragma unroll
    for (int mt = 0; mt < 4; ++mt)
        #pragma unroll
        for (int nt = 0; nt < 2; ++nt)
            #pragma unroll
            for (int r = 0; r < 4; ++r)
                acc[mt][nt][r] = f_from_bits(
                    zh[(size_t)rs[mt][r] * 256 + w * 32 + nt * 16 + cc]);

    // mole_frac pass-through for this block's rows (fused mf_copy)
    if (tid < 64) {
        out[(size_t)N_ROWS * 256 + n0 + tid] = mf[n0 + tid];
    }

    // stage [emb | mf | 0pad] as f16, stride AST
    for (int i = tid; i < 64 * 42; i += 512) {
        int r = i / 42, c4 = i - r * 42;
        int row = n0 + r;
        float x0 = 0.f, x1 = 0.f, x2 = 0.f, x3 = 0.f;
        if (c4 < 32) {
            const float4 v = *reinterpret_cast<const float4*>(&comp_emb[(size_t)row * EMB + c4 * 4]);
            x0 = v.x; x1 = v.y; x2 = v.z; x3 = v.w;
        } else if (c4 == 32) {
            x0 = mf[row];
        }
        uint2 hv = make_uint2((unsigned)h_bits((_Float16)x0) | ((unsigned)h_bits((_Float16)x1) << 16),
                              (unsigned)h_bits((_Float16)x2) | ((unsigned)h_bits((_Float16)x3) << 16));
        *reinterpret_cast<uint2*>(&lds[r * AST + c4 * 4]) = hv;
    }
    __syncthreads();

    // layer 1 (K=129, acc pre-seeded with z+gb1)
    KLOOP_P(S1, AIDX_L1, g1h)
    __syncthreads();
    WRITE_ACT_LDS()
    __syncthreads();
    // layer 2
    ACC_INIT_BIAS(gb2)
    KLOOP_P(S2, AIDX_SW, g2h)
    #pragma unroll
    for (int mt = 0; mt < 4; ++mt)
        #pragma unroll
        for (int nt = 0; nt < 2; ++nt)
            #pragma unroll
            for (int r = 0; r < 4; ++r)
                out[(size_t)(n0 + mt * 16 + 4 * g + r) * 256 + w * 32 + nt * 16 + cc] =
                    softplus_f(acc[mt][nt][r]);
}

extern "C" void kernel_launch(void* const* d_in, const int* in_sizes, int n_in,
                              void* d_out, int out_size, void* d_ws, size_t ws_size,
                              hipStream_t stream) {
    const float* comp_emb = (const float*)d_in[0];
    const float* mf       = (const float*)d_in[1];
    const int*   seg      = (const int*)d_in[2];
    const float* iW1      = (const float*)d_in[3];
    const float* ib1      = (const float*)d_in[4];
    const float* iW2      = (const float*)d_in[5];
    const float* ib2      = (const float*)d_in[6];
    const float* gW1      = (const float*)d_in[7];
    const float* gb1      = (const float*)d_in[8];
    const float* gW2      = (const float*)d_in[9];
    const float* gb2      = (const float*)d_in[10];
    float* out = (float*)d_out;

    // workspace layout:
    //   zh [M*256] u16 | f16 weight packs (278528 u16) | CSR ints
    unsigned short* zh  = (unsigned short*)d_ws;
    unsigned short* i1h = zh + (size_t)M_SEG * 256;
    unsigned short* i2h = i1h + 40960;
    unsigned short* g1h = i2h + 65536;
    unsigned short* gzh = g1h + 40960;
    unsigned short* g2h = gzh + 65536;
    int* counts_i = (int*)(g2h + 65536);
    int* cursor   = counts_i + M_SEG;
    int* excl     = cursor + M_SEG;
    int* rowids   = excl + M_SEG;
    int* partials    = rowids + N_ROWS;
    int* partials_ex = partials + 128;

    // zero only the small atomic counters (counts_i + cursor, adjacent)
    hipMemsetAsync(counts_i, 0, 2 * (size_t)M_SEG * sizeof(int), stream);

    // weight prepack (tiny)
    pack_w_kernel<<<20, 256, 0, stream>>>(iW1, 129, S1, i1h);
    pack_w_kernel<<<32, 256, 0, stream>>>(iW2, 256, S2, i2h);
    pack_w_kernel<<<20, 256, 0, stream>>>(gW1, 129, S1, g1h);              // emb|mf rows
    pack_w_kernel<<<32, 256, 0, stream>>>(gW1 + 129 * 256, 256, S2, gzh);  // ctx rows
    pack_w_kernel<<<32, 256, 0, stream>>>(gW2, 256, S2, g2h);

    // CSR build: count -> scan(3) -> scatter
    const int nb_rows = (N_ROWS + 255) / 256;
    const int nb_scan = (M_SEG + 1023) / 1024;      // 98
    count_kernel<<<nb_rows, 256, 0, stream>>>(seg, counts_i);
    scan_kernel<<<nb_scan, 256, 0, stream>>>(counts_i, excl, partials, M_SEG);
    scan_kernel<<<1, 256, 0, stream>>>(partials, partials_ex, nullptr, nb_scan);
    add_offsets_kernel<<<(M_SEG + 255) / 256, 256, 0, stream>>>(excl, partials_ex, M_SEG);
    scatter_kernel<<<nb_rows, 256, 0, stream>>>(seg, excl, cursor, rowids);

    mix_mfma_kernel<<<(M_SEG + 63) / 64, 512, 0, stream>>>(
        comp_emb, mf, rowids, excl, i1h, ib1, i2h, ib2, gzh, gb1, zh);
    gate_mfma_kernel<<<N_ROWS / 64, 512, 0, stream>>>(
        comp_emb, mf, seg, zh, g1h, g2h, gb2, out);
}